// Round 8
// baseline (2265.967 us; speedup 1.0000x reference)
//
#include <hip/hip_runtime.h>
#include <stdint.h>

#define NB 64
#define NBV 32         // viterbi blocks (2 batches per wave)
#define NT 2048
#define NC 128
#define KF 32          // forward chunks per batch
#define LF 64          // forward chunk length
#define WF 16          // forward warmup steps

typedef _Float16 h2 __attribute__((ext_vector_type(2)));

__device__ __forceinline__ h2 bc2(uint32_t u) { return __builtin_bit_cast(h2, u); }

__device__ __forceinline__ float fdot2f(h2 a, h2 b, float c) {
#if __has_builtin(__builtin_amdgcn_fdot2)
  return __builtin_amdgcn_fdot2(a, b, c, false);
#else
  float d;
  asm("v_dot2_f32_f16 %0, %1, %2, %3"
      : "=v"(d)
      : "v"(__builtin_bit_cast(uint32_t, a)), "v"(__builtin_bit_cast(uint32_t, b)), "v"(c));
  return d;
#endif
}

#define DPP_FMAX_STAGE(vv, ctrl)                                               \
  {                                                                            \
    int t_ = __builtin_amdgcn_update_dpp(vv, vv, ctrl, 0xf, 0xf, false);       \
    vv = __builtin_bit_cast(int, fmaxf(__builtin_bit_cast(float, vv),          \
                                       __builtin_bit_cast(float, t_)));        \
  }

__device__ __forceinline__ float wave_max_bcast(float x) {
  int v = __builtin_bit_cast(int, x);
  DPP_FMAX_STAGE(v, 0x111);
  DPP_FMAX_STAGE(v, 0x112);
  DPP_FMAX_STAGE(v, 0x114);
  DPP_FMAX_STAGE(v, 0x118);
  DPP_FMAX_STAGE(v, 0x142);
  DPP_FMAX_STAGE(v, 0x143);
  return __builtin_bit_cast(float, __builtin_amdgcn_readlane(v, 63));
}

__device__ __forceinline__ float readlanef(float v, int l) {
  return __builtin_bit_cast(float, __builtin_amdgcn_readlane(__builtin_bit_cast(int, v), l));
}

// Byte offset of one-hot row (b,t) inside d_out (floats: 64 nll + (b*T+t)*128).
// First 128 bytes of each 512B row slot temporarily hold uint8 backpointers.
__device__ __forceinline__ size_t slot_off(int b, int t) {
  return ((size_t)64 + ((size_t)b * NT + t) * NC) * 4;
}

union ScanSM {
  // viterbi: interleaved transitions, IT[l*256 + ct*2 + p] = T[2l+p][ct] (64KB).
  // One b128 at float offset (l*256 + 4*lane) yields
  // {T[2l][2lane], T[2l+1][2lane], T[2l][2lane+1], T[2l+1][2lane+1]}.
  float itr[64 * 256];
  uint32_t ea[4][2][64];      // forward: [wave][dbuf][lane] exp(alpha) fp16x2
};

// grid: blocks [0,NBV) = viterbi (wave 0 only, TWO batches per wave);
// [NBV, NBV+512) = forward, 4 independent chunk-waves per block.
__global__ __launch_bounds__(256, 1) void scan_kernel(
    const float* __restrict__ em, const float* __restrict__ trans,
    const float* __restrict__ startv, const float* __restrict__ endv,
    float* __restrict__ out, float* __restrict__ fpart, int* __restrict__ best_last) {
  __shared__ __align__(16) ScanSM sm;
  const int lane = threadIdx.x & 63;
  const int wid = threadIdx.x >> 6;

  if (blockIdx.x >= NBV) {
    // ================= forward chunks (log partition pieces) =================
    const int fi = (blockIdx.x - NBV) * 4 + wid;  // chunk id 0..2047
    const int b = fi >> 5, c = fi & 31;
    const int t0 = (c == 0) ? 0 : c * LF - WF;
    const int tend = (c == KF - 1) ? (NT - 1) : (c + 1) * LF;
    const float* emb = em + (size_t)b * NT * NC;

    h2 e0[64], e1[64];
#pragma unroll
    for (int j = 0; j < 64; ++j) {
      float2 r0 = *(const float2*)(trans + (size_t)(2 * j) * NC + 2 * lane);
      float2 r1 = *(const float2*)(trans + (size_t)(2 * j + 1) * NC + 2 * lane);
      h2 a, bb;
      a.x = (_Float16)__expf(r0.x);  a.y = (_Float16)__expf(r1.x);
      bb.x = (_Float16)__expf(r0.y); bb.y = (_Float16)__expf(r1.y);
      e0[j] = a; e1[j] = bb;
    }
    float2 ev = *(const float2*)(endv + 2 * lane);
    float2 em0 = *(const float2*)(emb + (size_t)t0 * NC + 2 * lane);
    float2 nx0 = *(const float2*)(emb + (size_t)(t0 + 1) * NC + 2 * lane);
    float2 nx1 = *(const float2*)(emb + (size_t)(t0 + 2) * NC + 2 * lane);
    float2 nx2 = *(const float2*)(emb + (size_t)(t0 + 3) * NC + 2 * lane);
    float2 nx3 = *(const float2*)(emb + (size_t)(t0 + 4) * NC + 2 * lane);
    float u0 = em0.x, u1 = em0.y;
    if (c == 0) {
      float2 sv = *(const float2*)(startv + 2 * lane);
      u0 += sv.x; u1 += sv.y;
    }
    float mu = 0.f;
    uint32_t* eab0 = &sm.ea[wid][0][0];
    uint32_t* eab1 = &sm.ea[wid][1][0];

    auto fstep = [&](int t, float2& nx) {
      h2 eh; eh.x = (_Float16)__expf(u0); eh.y = (_Float16)__expf(u1);
      uint32_t* eab = (t & 1) ? eab1 : eab0;
      eab[lane] = __builtin_bit_cast(uint32_t, eh);
      float nm = wave_max_bcast(fmaxf(u0, u1));  // overlaps LDS round-trip
      asm volatile("s_waitcnt lgkmcnt(0)" ::: "memory");
      float A0 = 0.f, A1 = 0.f, A2 = 0.f, A3 = 0.f;
#pragma unroll
      for (int q = 0; q < 16; ++q) {
        uint4 w = *(const uint4*)&eab[q * 4];
        A0 = fdot2f(bc2(w.x), e0[4 * q + 0], A0); A1 = fdot2f(bc2(w.x), e1[4 * q + 0], A1);
        A2 = fdot2f(bc2(w.y), e0[4 * q + 1], A2); A3 = fdot2f(bc2(w.y), e1[4 * q + 1], A3);
        A0 = fdot2f(bc2(w.z), e0[4 * q + 2], A0); A1 = fdot2f(bc2(w.z), e1[4 * q + 2], A1);
        A2 = fdot2f(bc2(w.w), e0[4 * q + 3], A2); A3 = fdot2f(bc2(w.w), e1[4 * q + 3], A3);
      }
      float o0 = nx.x - nm, o1 = nx.y - nm;
      u0 = __logf(A0 + A2) + o0;
      u1 = __logf(A1 + A3) + o1;
      mu += nm;
      if (t + 4 <= tend) nx = *(const float2*)(emb + (size_t)(t + 4) * NC + 2 * lane);
    };

    auto wave_lse = [&](float x0, float x1) -> float {
      float m = wave_max_bcast(fmaxf(x0, x1));
      float ss = __expf(x0 - m) + __expf(x1 - m);
#pragma unroll
      for (int s = 1; s < 64; s <<= 1) ss += __shfl_xor(ss, s, 64);
      return m + __logf(ss);
    };

    int t = t0 + 1;
    float m_start = 0.f;
    if (c > 0) {
      for (int j = 0; j < WF / 4; ++j) {
        fstep(t, nx0); fstep(t + 1, nx1); fstep(t + 2, nx2); fstep(t + 3, nx3);
        t += 4;
      }
      m_start = mu + wave_lse(u0, u1);
    }
    for (; t + 3 <= tend; t += 4) {
      fstep(t, nx0); fstep(t + 1, nx1); fstep(t + 2, nx2); fstep(t + 3, nx3);
    }
    int rem = tend - t + 1;  // 0..3
    if (rem > 0) fstep(t, nx0);
    if (rem > 1) fstep(t + 1, nx1);
    if (rem > 2) fstep(t + 2, nx2);

    float m_end;
    if (c == KF - 1) m_end = mu + wave_lse(u0 + ev.x, u1 + ev.y);
    else             m_end = mu + wave_lse(u0, u1);
    if (lane == 0) fpart[b * KF + c] = m_end - m_start;
  } else {
    // ========== viterbi (exact fp32, pruned max-plus), 2 batches/wave ==========
    if (wid != 0) return;
    const int bA = 2 * blockIdx.x, bB = bA + 1;
    const float* embA = em + (size_t)bA * NT * NC;
    const float* embB = em + (size_t)bB * NT * NC;
    char* ob = (char*)out;
    // build interleaved T
    for (int r = 0; r < NC; ++r) {
      float2 w = *(const float2*)(trans + (size_t)r * NC + 2 * lane);
      int l = r >> 1, p = r & 1;
      sm.itr[l * 256 + (2 * lane) * 2 + p] = w.x;
      sm.itr[l * 256 + (2 * lane + 1) * 2 + p] = w.y;
    }
    asm volatile("s_waitcnt lgkmcnt(0)" ::: "memory");
    // per-row max/min for exact pruning: lane owns rows 2*lane (x/z), 2*lane+1 (y/w)
    float rmx0 = -INFINITY, rmn0 = INFINITY, rmx1 = -INFINITY, rmn1 = INFINITY;
    for (int j = 0; j < 64; ++j) {
      int jj = (j + lane) & 63;
      float4 q = *(const float4*)&sm.itr[lane * 256 + jj * 4];
      rmx0 = fmaxf(rmx0, fmaxf(q.x, q.z)); rmn0 = fminf(rmn0, fminf(q.x, q.z));
      rmx1 = fmaxf(rmx1, fmaxf(q.y, q.w)); rmn1 = fminf(rmn1, fminf(q.y, q.w));
    }

    float2 sv = *(const float2*)(startv + 2 * lane);
    float2 ev = *(const float2*)(endv + 2 * lane);
    float2 emA0 = *(const float2*)(embA + 2 * lane);
    float2 emB0 = *(const float2*)(embB + 2 * lane);
    float2 nxA0 = *(const float2*)(embA + (size_t)1 * NC + 2 * lane);
    float2 nxA1 = *(const float2*)(embA + (size_t)2 * NC + 2 * lane);
    float2 nxA2 = *(const float2*)(embA + (size_t)3 * NC + 2 * lane);
    float2 nxA3 = *(const float2*)(embA + (size_t)4 * NC + 2 * lane);
    float2 nxB0 = *(const float2*)(embB + (size_t)1 * NC + 2 * lane);
    float2 nxB1 = *(const float2*)(embB + (size_t)2 * NC + 2 * lane);
    float2 nxB2 = *(const float2*)(embB + (size_t)3 * NC + 2 * lane);
    float2 nxB3 = *(const float2*)(embB + (size_t)4 * NC + 2 * lane);
    float v0A = sv.x + emA0.x, v1A = sv.y + emA0.y;
    float v0B = sv.x + emB0.x, v1B = sv.y + emB0.y;
    const float4* itb = (const float4*)&sm.itr[4 * lane];

    // r4-proven branchy PROC: skip invalid parity; ascending cf + strict '>'
    // == first-index argmax (duplicate re-processing is idempotent).
    auto PROC = [&](int lc, float4 q, unsigned long long m0, unsigned long long m1,
                    float v0, float v1, float& b0, float& b1, int& i0, int& i1) {
      if ((m0 >> lc) & 1ull) {
        float vce = readlanef(v0, lc);
        float s0 = vce + q.x, s1 = vce + q.z;
        bool g0 = s0 > b0; b0 = g0 ? s0 : b0; i0 = g0 ? 2 * lc : i0;
        bool g1 = s1 > b1; b1 = g1 ? s1 : b1; i1 = g1 ? 2 * lc : i1;
      }
      if ((m1 >> lc) & 1ull) {
        float vco = readlanef(v1, lc);
        float s0 = vco + q.y, s1 = vco + q.w;
        bool g0 = s0 > b0; b0 = g0 ? s0 : b0; i0 = g0 ? 2 * lc + 1 : i0;
        bool g1 = s1 > b1; b1 = g1 ? s1 : b1; i1 = g1 ? 2 * lc + 1 : i1;
      }
    };
    // rare leftover loop (survivors > 4), r4 group-of-4 mechanics
    auto slow = [&](unsigned long long rem, unsigned long long m0, unsigned long long m1,
                    float v0, float v1, float& b0, float& b1, int& i0, int& i1) {
      do {
        int l0 = (int)__builtin_ctzll(rem); rem &= rem - 1;
        int l1 = l0, l2 = l0, l3 = l0;
        if (rem) {
          l1 = (int)__builtin_ctzll(rem); rem &= rem - 1;
          if (rem) {
            l2 = (int)__builtin_ctzll(rem); rem &= rem - 1;
            if (rem) { l3 = (int)__builtin_ctzll(rem); rem &= rem - 1; }
          }
        }
        float4 q0 = itb[l0 * 64], q1 = itb[l1 * 64], q2 = itb[l2 * 64], q3 = itb[l3 * 64];
        PROC(l0, q0, m0, m1, v0, v1, b0, b1, i0, i1);
        PROC(l1, q1, m0, m1, v0, v1, b0, b1, i0, i1);
        PROC(l2, q2, m0, m1, v0, v1, b0, b1, i0, i1);
        PROC(l3, q3, m0, m1, v0, v1, b0, b1, i0, i1);
      } while (rem);
    };

    auto vstep = [&](int t, float2& nxA, float2& nxB) {
      // two independent chains fused: compiler fills A's stalls with B's work
      float thrA = wave_max_bcast(fmaxf(v0A + rmn0, v1A + rmn1));
      float thrB = wave_max_bcast(fmaxf(v0B + rmn0, v1B + rmn1));
      unsigned long long m0A = __ballot(v0A + rmx0 >= thrA);
      unsigned long long m1A = __ballot(v1A + rmx1 >= thrA);
      unsigned long long m0B = __ballot(v0B + rmx0 >= thrB);
      unsigned long long m1B = __ballot(v1B + rmx1 >= thrB);
      float bA0 = -INFINITY, bA1 = -INFINITY, bB0 = -INFINITY, bB1 = -INFINITY;
      int iA0 = 0, iA1 = 0, iB0 = 0, iB1 = 0;
      unsigned long long remA = m0A | m1A; if (!remA) remA = 1ull;
      unsigned long long remB = m0B | m1B; if (!remB) remB = 1ull;
      // branchless first-4 enumeration per chain (pad = dup of first)
      int a0 = (int)__builtin_ctzll(remA); remA &= remA - 1;
      int a1 = remA ? (int)__builtin_ctzll(remA) : a0; remA = remA ? (remA & (remA - 1)) : 0ull;
      int a2 = remA ? (int)__builtin_ctzll(remA) : a0; remA = remA ? (remA & (remA - 1)) : 0ull;
      int a3 = remA ? (int)__builtin_ctzll(remA) : a0; remA = remA ? (remA & (remA - 1)) : 0ull;
      int c0 = (int)__builtin_ctzll(remB); remB &= remB - 1;
      int c1 = remB ? (int)__builtin_ctzll(remB) : c0; remB = remB ? (remB & (remB - 1)) : 0ull;
      int c2 = remB ? (int)__builtin_ctzll(remB) : c0; remB = remB ? (remB & (remB - 1)) : 0ull;
      int c3 = remB ? (int)__builtin_ctzll(remB) : c0; remB = remB ? (remB & (remB - 1)) : 0ull;
      // 8 x ds_read_b128, one latency window
      float4 qA0 = itb[a0 * 64], qA1 = itb[a1 * 64], qA2 = itb[a2 * 64], qA3 = itb[a3 * 64];
      float4 qB0 = itb[c0 * 64], qB1 = itb[c1 * 64], qB2 = itb[c2 * 64], qB3 = itb[c3 * 64];
      PROC(a0, qA0, m0A, m1A, v0A, v1A, bA0, bA1, iA0, iA1);
      PROC(a1, qA1, m0A, m1A, v0A, v1A, bA0, bA1, iA0, iA1);
      PROC(a2, qA2, m0A, m1A, v0A, v1A, bA0, bA1, iA0, iA1);
      PROC(a3, qA3, m0A, m1A, v0A, v1A, bA0, bA1, iA0, iA1);
      PROC(c0, qB0, m0B, m1B, v0B, v1B, bB0, bB1, iB0, iB1);
      PROC(c1, qB1, m0B, m1B, v0B, v1B, bB0, bB1, iB0, iB1);
      PROC(c2, qB2, m0B, m1B, v0B, v1B, bB0, bB1, iB0, iB1);
      PROC(c3, qB3, m0B, m1B, v0B, v1B, bB0, bB1, iB0, iB1);
      if (remA) slow(remA, m0A, m1A, v0A, v1A, bA0, bA1, iA0, iA1);
      if (remB) slow(remB, m0B, m1B, v0B, v1B, bB0, bB1, iB0, iB1);
      v0A = bA0 + nxA.x; v1A = bA1 + nxA.y;
      v0B = bB0 + nxB.x; v1B = bB1 + nxB.y;
      if (t + 4 < NT) {
        nxA = *(const float2*)(embA + (size_t)(t + 4) * NC + 2 * lane);
        nxB = *(const float2*)(embB + (size_t)(t + 4) * NC + 2 * lane);
      }
      *(uint16_t*)(ob + slot_off(bA, t) + 2 * lane) =
          (uint16_t)((iA0 & 0xff) | (iA1 << 8));
      *(uint16_t*)(ob + slot_off(bB, t) + 2 * lane) =
          (uint16_t)((iB0 & 0xff) | (iB1 << 8));
    };
    int t = 1;
    for (; t + 3 < NT; t += 4) {
      vstep(t, nxA0, nxB0); vstep(t + 1, nxA1, nxB1);
      vstep(t + 2, nxA2, nxB2); vstep(t + 3, nxA3, nxB3);
    }
    vstep(t, nxA0, nxB0); vstep(t + 1, nxA1, nxB1); vstep(t + 2, nxA2, nxB2);

    auto finish = [&](float v0, float v1, int b) {
      float bv = v0; int bix = 2 * lane;
      if (v1 > bv) { bv = v1; bix = 2 * lane + 1; }
#pragma unroll
      for (int s = 1; s < 64; s <<= 1) {
        float ovv = __shfl_xor(bv, s, 64);
        int oi = __shfl_xor(bix, s, 64);
        if (ovv > bv || (ovv == bv && oi < bix)) { bv = ovv; bix = oi; }
      }
      if (lane == 0) best_last[b] = bix;
    };
    finish(v0A + ev.x, v1A + ev.y, bA);
    finish(v0B + ev.x, v1B + ev.y, bB);
  }
}

__global__ __launch_bounds__(256) void gold_kernel(
    const float* __restrict__ em, const int* __restrict__ tags,
    const float* __restrict__ trans, const float* __restrict__ startv,
    const float* __restrict__ endv, float* __restrict__ gold) {
  __shared__ float red[256];
  int b = blockIdx.x, tid = threadIdx.x;
  const float* emb = em + (size_t)b * NT * NC;
  const int* tgb = tags + (size_t)b * NT;
  float acc = 0.f;
  for (int j = 0; j < NT / 256; ++j) {
    int t = tid + j * 256;
    int tg = tgb[t];
    acc += emb[(size_t)t * NC + tg];
    if (t < NT - 1) acc += trans[(size_t)tg * NC + tgb[t + 1]];
  }
  red[tid] = acc;
  __syncthreads();
  for (int s = 128; s > 0; s >>= 1) { if (tid < s) red[tid] += red[tid + s]; __syncthreads(); }
  if (tid == 0) gold[b] = red[0] + startv[tgb[0]] + endv[tgb[NT - 1]];
}

// Per (b,chunk): compose backpointers over the chunk -> 128->128 map.
__global__ __launch_bounds__(128) void maps_kernel(const float* __restrict__ out,
                                                   uint8_t* __restrict__ mmap) {
  __shared__ uint8_t bp[256 * 128];
  int bid = blockIdx.x, b = bid >> 3, c = bid & 7, tid = threadIdx.x;
  const char* ob = (const char*)out;
  int lo_t = c * 256 + 1;
  int nrows = (c == 7) ? 255 : 256;
  int nd = nrows * 32;
  for (int k = 0; k < 64; ++k) {
    int d = tid + k * 128;
    if (d < nd) {
      int row = d >> 5, col = d & 31;
      *(uint32_t*)&bp[(size_t)d * 4] =
          *(const uint32_t*)(ob + slot_off(b, lo_t + row) + (size_t)col * 4);
    }
  }
  __syncthreads();
  int cur = tid;
  for (int i = nrows - 1; i >= 0; --i) cur = bp[i * 128 + cur];
  mmap[b * 1024 + c * 128 + tid] = (uint8_t)cur;
}

// Combine maps: boundary states per chunk; also nll = sum(fpart) - gold.
__global__ void boundary_kernel(const uint8_t* __restrict__ mmap,
                                const int* __restrict__ best_last,
                                const float* __restrict__ fpart,
                                const float* __restrict__ gold,
                                uint8_t* __restrict__ TOPa,
                                float* __restrict__ out) {
  int b = threadIdx.x;
  const uint8_t* ob = (const uint8_t*)out;
  int e = best_last[b];                       // = path[2047]
  for (int c = 7; c >= 0; --c) {
    TOPa[b * 8 + c] = (c == 7) ? (uint8_t)e : ob[slot_off(b, 256 * (c + 1)) + e];
    e = mmap[b * 1024 + c * 128 + e];         // e = path[256c]
  }
  float z = 0.f;
  for (int c = 0; c < KF; ++c) z += fpart[b * KF + c];
  out[b] = z - gold[b];
}

// Replay each chunk from its known top state, emit one-hot rows (overwrites bp region).
__global__ __launch_bounds__(128) void replay_kernel(float* __restrict__ out,
                                                     const uint8_t* __restrict__ TOPa) {
  __shared__ uint8_t bp[255 * 128];
  __shared__ uint8_t path[256];
  int bid = blockIdx.x, b = bid >> 3, c = bid & 7, tid = threadIdx.x;
  char* ob = (char*)out;
  int lo_t = c * 256 + 1;
  const int nd = 255 * 32;
  for (int k = 0; k < 64; ++k) {
    int d = tid + k * 128;
    if (d < nd) {
      int row = d >> 5, col = d & 31;
      *(uint32_t*)&bp[(size_t)d * 4] =
          *(const uint32_t*)(ob + slot_off(b, lo_t + row) + (size_t)col * 4);
    }
  }
  __syncthreads();
  if (tid == 0) {
    int cur = TOPa[b * 8 + c];
    path[255] = (uint8_t)cur;
    for (int i = 254; i >= 0; --i) { cur = bp[i * 128 + cur]; path[i] = (uint8_t)cur; }
  }
  __syncthreads();
  for (int k = 0; k < 64; ++k) {
    int idx = tid + k * 128;
    int row = idx >> 5, j = idx & 31;
    int p = path[row];
    int c0 = j * 4;
    float4 val;
    val.x = (c0 + 0 == p) ? 1.f : 0.f;
    val.y = (c0 + 1 == p) ? 1.f : 0.f;
    val.z = (c0 + 2 == p) ? 1.f : 0.f;
    val.w = (c0 + 3 == p) ? 1.f : 0.f;
    *(float4*)(ob + slot_off(b, c * 256 + row) + (size_t)j * 16) = val;
  }
}

extern "C" void kernel_launch(void* const* d_in, const int* in_sizes, int n_in,
                              void* d_out, int out_size, void* d_ws, size_t ws_size,
                              hipStream_t stream) {
  const float* em = (const float*)d_in[0];
  const int* tags = (const int*)d_in[1];
  const float* trans = (const float*)d_in[2];
  const float* startv = (const float*)d_in[3];
  const float* endv = (const float*)d_in[4];
  float* out = (float*)d_out;
  char* ws = (char*)d_ws;
  float* fpart = (float*)(ws + 0);         // 64*32 f32 (8KB)
  float* gold = (float*)(ws + 8192);       // 64 f32
  int* best_last = (int*)(ws + 8448);      // 64 i32
  uint8_t* TOPa = (uint8_t*)(ws + 8704);   // 64*8 u8
  uint8_t* mmap = (uint8_t*)(ws + 9216);   // 64*1024 u8

  scan_kernel<<<dim3(NBV + 512), dim3(256), 0, stream>>>(em, trans, startv, endv, out,
                                                         fpart, best_last);
  gold_kernel<<<dim3(64), dim3(256), 0, stream>>>(em, tags, trans, startv, endv, gold);
  maps_kernel<<<dim3(512), dim3(128), 0, stream>>>(out, mmap);
  boundary_kernel<<<dim3(1), dim3(64), 0, stream>>>(mmap, best_last, fpart, gold, TOPa, out);
  replay_kernel<<<dim3(512), dim3(128), 0, stream>>>(out, TOPa);
}

// Round 9
// 1328.354 us; speedup vs baseline: 1.7058x; 1.7058x over previous
//
#include <hip/hip_runtime.h>
#include <stdint.h>

#define NB 64
#define NT 2048
#define NC 128
#define KF 32          // forward chunks per batch
#define LF 64          // forward chunk length
#define WF 16          // forward warmup steps
#define NDUMMY 128     // clock-keeper blocks

typedef _Float16 h2 __attribute__((ext_vector_type(2)));

__device__ __forceinline__ h2 bc2(uint32_t u) { return __builtin_bit_cast(h2, u); }

__device__ __forceinline__ float fdot2f(h2 a, h2 b, float c) {
#if __has_builtin(__builtin_amdgcn_fdot2)
  return __builtin_amdgcn_fdot2(a, b, c, false);
#else
  float d;
  asm("v_dot2_f32_f16 %0, %1, %2, %3"
      : "=v"(d)
      : "v"(__builtin_bit_cast(uint32_t, a)), "v"(__builtin_bit_cast(uint32_t, b)), "v"(c));
  return d;
#endif
}

#define DPP_FMAX_STAGE(vv, ctrl)                                               \
  {                                                                            \
    int t_ = __builtin_amdgcn_update_dpp(vv, vv, ctrl, 0xf, 0xf, false);       \
    vv = __builtin_bit_cast(int, fmaxf(__builtin_bit_cast(float, vv),          \
                                       __builtin_bit_cast(float, t_)));        \
  }

__device__ __forceinline__ float wave_max_bcast(float x) {
  int v = __builtin_bit_cast(int, x);
  DPP_FMAX_STAGE(v, 0x111);
  DPP_FMAX_STAGE(v, 0x112);
  DPP_FMAX_STAGE(v, 0x114);
  DPP_FMAX_STAGE(v, 0x118);
  DPP_FMAX_STAGE(v, 0x142);
  DPP_FMAX_STAGE(v, 0x143);
  return __builtin_bit_cast(float, __builtin_amdgcn_readlane(v, 63));
}

__device__ __forceinline__ float readlanef(float v, int l) {
  return __builtin_bit_cast(float, __builtin_amdgcn_readlane(__builtin_bit_cast(int, v), l));
}

// Byte offset of one-hot row (b,t) inside d_out (floats: 64 nll + (b*T+t)*128).
// First 128 bytes of each 512B row slot temporarily hold uint8 backpointers.
__device__ __forceinline__ size_t slot_off(int b, int t) {
  return ((size_t)64 + ((size_t)b * NT + t) * NC) * 4;
}

union ScanSM {
  float tr[NC * NC];          // viterbi: fp32 transitions (64KB)
  uint32_t ea[4][2][64];      // forward: [wave][dbuf][lane] exp(alpha) fp16x2
};

// grid: [0,NB) viterbi (wave 0 only); [NB, NB+512) forward, 4 chunk-waves per
// block; [NB+512, NB+512+NDUMMY) clock-keeper spin blocks (keep DVFS high
// during the serial viterbi tail; exit via device-scope done counter).
__global__ __launch_bounds__(256, 1) void scan_kernel(
    const float* __restrict__ em, const float* __restrict__ trans,
    const float* __restrict__ startv, const float* __restrict__ endv,
    float* __restrict__ out, float* __restrict__ fpart, int* __restrict__ best_last,
    int* __restrict__ done_cnt) {
  __shared__ __align__(16) ScanSM sm;
  const int lane = threadIdx.x & 63;
  const int wid = threadIdx.x >> 6;

  if (blockIdx.x >= NB + 512) {
    // ================= clock-keeper: dependent FMA spin, poll done ===========
    float x = (float)(threadIdx.x + 1) * 1e-9f + (float)blockIdx.x;
    for (int it = 0; it < 20000; ++it) {
#pragma unroll
      for (int k = 0; k < 256; ++k) x = __builtin_fmaf(x, 0.9999999f, 1e-7f);
      asm volatile("" ::"v"(x));
      if (atomicAdd(done_cnt, 0) >= NB) break;  // device-coherent read
    }
    return;
  }

  if (blockIdx.x >= NB) {
    // ================= forward chunks (log partition pieces) =================
    const int fi = (blockIdx.x - NB) * 4 + wid;   // chunk id 0..2047
    const int b = fi >> 5, c = fi & 31;
    const int t0 = (c == 0) ? 0 : c * LF - WF;
    const int tend = (c == KF - 1) ? (NT - 1) : (c + 1) * LF;
    const float* emb = em + (size_t)b * NT * NC;

    h2 e0[64], e1[64];
#pragma unroll
    for (int j = 0; j < 64; ++j) {
      float2 r0 = *(const float2*)(trans + (size_t)(2 * j) * NC + 2 * lane);
      float2 r1 = *(const float2*)(trans + (size_t)(2 * j + 1) * NC + 2 * lane);
      h2 a, bb;
      a.x = (_Float16)__expf(r0.x);  a.y = (_Float16)__expf(r1.x);
      bb.x = (_Float16)__expf(r0.y); bb.y = (_Float16)__expf(r1.y);
      e0[j] = a; e1[j] = bb;
    }
    float2 ev = *(const float2*)(endv + 2 * lane);
    float2 em0 = *(const float2*)(emb + (size_t)t0 * NC + 2 * lane);
    float2 nx0 = *(const float2*)(emb + (size_t)(t0 + 1) * NC + 2 * lane);
    float2 nx1 = *(const float2*)(emb + (size_t)(t0 + 2) * NC + 2 * lane);
    float2 nx2 = *(const float2*)(emb + (size_t)(t0 + 3) * NC + 2 * lane);
    float2 nx3 = *(const float2*)(emb + (size_t)(t0 + 4) * NC + 2 * lane);
    float u0 = em0.x, u1 = em0.y;
    if (c == 0) {
      float2 sv = *(const float2*)(startv + 2 * lane);
      u0 += sv.x; u1 += sv.y;
    }
    float mu = 0.f;
    uint32_t* eab0 = &sm.ea[wid][0][0];
    uint32_t* eab1 = &sm.ea[wid][1][0];

    auto fstep = [&](int t, float2& nx) {
      h2 eh; eh.x = (_Float16)__expf(u0); eh.y = (_Float16)__expf(u1);
      uint32_t* eab = (t & 1) ? eab1 : eab0;
      eab[lane] = __builtin_bit_cast(uint32_t, eh);
      float nm = wave_max_bcast(fmaxf(u0, u1));  // overlaps LDS round-trip
      asm volatile("s_waitcnt lgkmcnt(0)" ::: "memory");
      float A0 = 0.f, A1 = 0.f, A2 = 0.f, A3 = 0.f;
#pragma unroll
      for (int q = 0; q < 16; ++q) {
        uint4 w = *(const uint4*)&eab[q * 4];
        A0 = fdot2f(bc2(w.x), e0[4 * q + 0], A0); A1 = fdot2f(bc2(w.x), e1[4 * q + 0], A1);
        A2 = fdot2f(bc2(w.y), e0[4 * q + 1], A2); A3 = fdot2f(bc2(w.y), e1[4 * q + 1], A3);
        A0 = fdot2f(bc2(w.z), e0[4 * q + 2], A0); A1 = fdot2f(bc2(w.z), e1[4 * q + 2], A1);
        A2 = fdot2f(bc2(w.w), e0[4 * q + 3], A2); A3 = fdot2f(bc2(w.w), e1[4 * q + 3], A3);
      }
      float o0 = nx.x - nm, o1 = nx.y - nm;
      u0 = __logf(A0 + A2) + o0;
      u1 = __logf(A1 + A3) + o1;
      mu += nm;
      if (t + 4 <= tend) nx = *(const float2*)(emb + (size_t)(t + 4) * NC + 2 * lane);
    };

    auto wave_lse = [&](float x0, float x1) -> float {
      float m = wave_max_bcast(fmaxf(x0, x1));
      float ss = __expf(x0 - m) + __expf(x1 - m);
#pragma unroll
      for (int s = 1; s < 64; s <<= 1) ss += __shfl_xor(ss, s, 64);
      return m + __logf(ss);
    };

    int t = t0 + 1;
    float m_start = 0.f;
    if (c > 0) {
      for (int j = 0; j < WF / 4; ++j) {
        fstep(t, nx0); fstep(t + 1, nx1); fstep(t + 2, nx2); fstep(t + 3, nx3);
        t += 4;
      }
      m_start = mu + wave_lse(u0, u1);
    }
    for (; t + 3 <= tend; t += 4) {
      fstep(t, nx0); fstep(t + 1, nx1); fstep(t + 2, nx2); fstep(t + 3, nx3);
    }
    int rem = tend - t + 1;  // 0..3
    if (rem > 0) fstep(t, nx0);
    if (rem > 1) fstep(t + 1, nx1);
    if (rem > 2) fstep(t + 2, nx2);

    float m_end;
    if (c == KF - 1) m_end = mu + wave_lse(u0 + ev.x, u1 + ev.y);
    else             m_end = mu + wave_lse(u0, u1);
    if (lane == 0) fpart[b * KF + c] = m_end - m_start;
  } else {
    // ================= viterbi (exact fp32, pruned max-plus) ==================
    // r4-proven loop mechanics (the 1257us best), verbatim.
    if (wid != 0) return;
    const int b = blockIdx.x;
    const float* emb = em + (size_t)b * NT * NC;
    char* ob = (char*)out;
    float* smv = sm.tr;
#pragma unroll 8
    for (int r = 0; r < NC; ++r) {
      *(float2*)&smv[r * NC + 2 * lane] =
          *(const float2*)(trans + (size_t)r * NC + 2 * lane);
    }
    // per-row max/min for exact pruning: rmx0/rmn0 row 2*lane, rmx1/rmn1 row 2*lane+1
    float rmx0 = -INFINITY, rmn0 = INFINITY, rmx1 = -INFINITY, rmn1 = INFINITY;
    {
      const float* r0 = &smv[(2 * lane) * NC];
      const float* r1 = &smv[(2 * lane + 1) * NC];
      for (int j = 0; j < 32; ++j) {
        int k = ((lane + j) & 31) * 4;
        float4 a = *(const float4*)(r0 + k);
        float4 bq = *(const float4*)(r1 + k);
        rmx0 = fmaxf(rmx0, fmaxf(fmaxf(a.x, a.y), fmaxf(a.z, a.w)));
        rmn0 = fminf(rmn0, fminf(fminf(a.x, a.y), fminf(a.z, a.w)));
        rmx1 = fmaxf(rmx1, fmaxf(fmaxf(bq.x, bq.y), fmaxf(bq.z, bq.w)));
        rmn1 = fminf(rmn1, fminf(fminf(bq.x, bq.y), fminf(bq.z, bq.w)));
      }
    }

    float2 sv = *(const float2*)(startv + 2 * lane);
    float2 ev = *(const float2*)(endv + 2 * lane);
    float2 em0 = *(const float2*)(emb + 2 * lane);
    float2 nx0 = *(const float2*)(emb + (size_t)1 * NC + 2 * lane);
    float2 nx1 = *(const float2*)(emb + (size_t)2 * NC + 2 * lane);
    float2 nx2 = *(const float2*)(emb + (size_t)3 * NC + 2 * lane);
    float2 nx3 = *(const float2*)(emb + (size_t)4 * NC + 2 * lane);
    float v0 = sv.x + em0.x, v1 = sv.y + em0.y;  // v[2*lane], v[2*lane+1]

    auto vstep = [&](int t, float2& nx) {
      // thr = max_cf fl(v[cf]+rowmin[cf]) <= winner(ct) for every ct (fp-monotone)
      float thr = wave_max_bcast(fmaxf(v0 + rmn0, v1 + rmn1));
      unsigned long long m0 = __ballot(v0 + rmx0 >= thr);   // even cf = 2*l
      unsigned long long m1 = __ballot(v1 + rmx1 >= thr);   // odd  cf = 2*l+1
      float best0 = -INFINITY, best1 = -INFINITY;
      int bi0 = 0, bi1 = 0;

      auto proc = [&](int lc, float2 te, float2 to) {
        float vce = readlanef(v0, lc);
        float vco = readlanef(v1, lc);
        // ascending cf + strict '>' == first-index argmax; duplicates idempotent
        if ((m0 >> lc) & 1ull) {
          float s0 = vce + te.x, s1 = vce + te.y;
          bool g0 = s0 > best0; best0 = g0 ? s0 : best0; bi0 = g0 ? 2 * lc : bi0;
          bool g1 = s1 > best1; best1 = g1 ? s1 : best1; bi1 = g1 ? 2 * lc : bi1;
        }
        if ((m1 >> lc) & 1ull) {
          float s0 = vco + to.x, s1 = vco + to.y;
          bool g0 = s0 > best0; best0 = g0 ? s0 : best0; bi0 = g0 ? 2 * lc + 1 : bi0;
          bool g1 = s1 > best1; best1 = g1 ? s1 : best1; bi1 = g1 ? 2 * lc + 1 : bi1;
        }
      };

      unsigned long long rem = m0 | m1;   // never empty (thr-achiever qualifies)
      do {
        int l0 = (int)__builtin_ctzll(rem); rem &= rem - 1;
        int l1 = l0, l2 = l0, l3 = l0;
        if (rem) {
          l1 = (int)__builtin_ctzll(rem); rem &= rem - 1;
          if (rem) {
            l2 = (int)__builtin_ctzll(rem); rem &= rem - 1;
            if (rem) { l3 = (int)__builtin_ctzll(rem); rem &= rem - 1; }
          }
        }
        // batch-issue all 8 LDS reads for the group -> one latency wait
        const float2 teA = *(const float2*)&smv[(2 * l0) * NC + 2 * lane];
        const float2 toA = *(const float2*)&smv[(2 * l0) * NC + NC + 2 * lane];
        const float2 teB = *(const float2*)&smv[(2 * l1) * NC + 2 * lane];
        const float2 toB = *(const float2*)&smv[(2 * l1) * NC + NC + 2 * lane];
        const float2 teC = *(const float2*)&smv[(2 * l2) * NC + 2 * lane];
        const float2 toC = *(const float2*)&smv[(2 * l2) * NC + NC + 2 * lane];
        const float2 teD = *(const float2*)&smv[(2 * l3) * NC + 2 * lane];
        const float2 toD = *(const float2*)&smv[(2 * l3) * NC + NC + 2 * lane];
        proc(l0, teA, toA);
        proc(l1, teB, toB);
        proc(l2, teC, toC);
        proc(l3, teD, toD);
      } while (rem);

      v0 = best0 + nx.x; v1 = best1 + nx.y;
      if (t + 4 < NT) nx = *(const float2*)(emb + (size_t)(t + 4) * NC + 2 * lane);
      uint16_t pkd = (uint16_t)((bi0 & 0xff) | (bi1 << 8));
      *(uint16_t*)(ob + slot_off(b, t) + 2 * lane) = pkd;  // bp bytes into d_out slot
    };
    int t = 1;
    for (; t + 3 < NT; t += 4) { vstep(t, nx0); vstep(t + 1, nx1); vstep(t + 2, nx2); vstep(t + 3, nx3); }
    vstep(t, nx0); vstep(t + 1, nx1); vstep(t + 2, nx2);  // t = 2045..2047

    v0 += ev.x; v1 += ev.y;
    float bv = v0; int bix = 2 * lane;
    if (v1 > bv) { bv = v1; bix = 2 * lane + 1; }
#pragma unroll
    for (int s = 1; s < 64; s <<= 1) {
      float ovv = __shfl_xor(bv, s, 64);
      int oi = __shfl_xor(bix, s, 64);
      if (ovv > bv || (ovv == bv && oi < bix)) { bv = ovv; bix = oi; }
    }
    if (lane == 0) {
      best_last[b] = bix;
      atomicAdd(done_cnt, 1);   // device-scope: releases the clock-keepers
    }
  }
}

__global__ __launch_bounds__(256) void gold_kernel(
    const float* __restrict__ em, const int* __restrict__ tags,
    const float* __restrict__ trans, const float* __restrict__ startv,
    const float* __restrict__ endv, float* __restrict__ gold) {
  __shared__ float red[256];
  int b = blockIdx.x, tid = threadIdx.x;
  const float* emb = em + (size_t)b * NT * NC;
  const int* tgb = tags + (size_t)b * NT;
  float acc = 0.f;
  for (int j = 0; j < NT / 256; ++j) {
    int t = tid + j * 256;
    int tg = tgb[t];
    acc += emb[(size_t)t * NC + tg];
    if (t < NT - 1) acc += trans[(size_t)tg * NC + tgb[t + 1]];
  }
  red[tid] = acc;
  __syncthreads();
  for (int s = 128; s > 0; s >>= 1) { if (tid < s) red[tid] += red[tid + s]; __syncthreads(); }
  if (tid == 0) gold[b] = red[0] + startv[tgb[0]] + endv[tgb[NT - 1]];
}

// Per (b,chunk): compose backpointers over the chunk -> 128->128 map.
__global__ __launch_bounds__(128) void maps_kernel(const float* __restrict__ out,
                                                   uint8_t* __restrict__ mmap) {
  __shared__ uint8_t bp[256 * 128];
  int bid = blockIdx.x, b = bid >> 3, c = bid & 7, tid = threadIdx.x;
  const char* ob = (const char*)out;
  int lo_t = c * 256 + 1;
  int nrows = (c == 7) ? 255 : 256;
  int nd = nrows * 32;
  for (int k = 0; k < 64; ++k) {
    int d = tid + k * 128;
    if (d < nd) {
      int row = d >> 5, col = d & 31;
      *(uint32_t*)&bp[(size_t)d * 4] =
          *(const uint32_t*)(ob + slot_off(b, lo_t + row) + (size_t)col * 4);
    }
  }
  __syncthreads();
  int cur = tid;
  for (int i = nrows - 1; i >= 0; --i) cur = bp[i * 128 + cur];
  mmap[b * 1024 + c * 128 + tid] = (uint8_t)cur;
}

// Combine maps: boundary states per chunk; also nll = sum(fpart) - gold.
__global__ void boundary_kernel(const uint8_t* __restrict__ mmap,
                                const int* __restrict__ best_last,
                                const float* __restrict__ fpart,
                                const float* __restrict__ gold,
                                uint8_t* __restrict__ TOPa,
                                float* __restrict__ out) {
  int b = threadIdx.x;
  const uint8_t* ob = (const uint8_t*)out;
  int e = best_last[b];                       // = path[2047]
  for (int c = 7; c >= 0; --c) {
    TOPa[b * 8 + c] = (c == 7) ? (uint8_t)e : ob[slot_off(b, 256 * (c + 1)) + e];
    e = mmap[b * 1024 + c * 128 + e];         // e = path[256c]
  }
  float z = 0.f;
  for (int c = 0; c < KF; ++c) z += fpart[b * KF + c];
  out[b] = z - gold[b];
}

// Replay each chunk from its known top state, emit one-hot rows (overwrites bp region).
__global__ __launch_bounds__(128) void replay_kernel(float* __restrict__ out,
                                                     const uint8_t* __restrict__ TOPa) {
  __shared__ uint8_t bp[255 * 128];
  __shared__ uint8_t path[256];
  int bid = blockIdx.x, b = bid >> 3, c = bid & 7, tid = threadIdx.x;
  char* ob = (char*)out;
  int lo_t = c * 256 + 1;
  const int nd = 255 * 32;
  for (int k = 0; k < 64; ++k) {
    int d = tid + k * 128;
    if (d < nd) {
      int row = d >> 5, col = d & 31;
      *(uint32_t*)&bp[(size_t)d * 4] =
          *(const uint32_t*)(ob + slot_off(b, lo_t + row) + (size_t)col * 4);
    }
  }
  __syncthreads();
  if (tid == 0) {
    int cur = TOPa[b * 8 + c];
    path[255] = (uint8_t)cur;
    for (int i = 254; i >= 0; --i) { cur = bp[i * 128 + cur]; path[i] = (uint8_t)cur; }
  }
  __syncthreads();
  for (int k = 0; k < 64; ++k) {
    int idx = tid + k * 128;
    int row = idx >> 5, j = idx & 31;
    int p = path[row];
    int c0 = j * 4;
    float4 val;
    val.x = (c0 + 0 == p) ? 1.f : 0.f;
    val.y = (c0 + 1 == p) ? 1.f : 0.f;
    val.z = (c0 + 2 == p) ? 1.f : 0.f;
    val.w = (c0 + 3 == p) ? 1.f : 0.f;
    *(float4*)(ob + slot_off(b, c * 256 + row) + (size_t)j * 16) = val;
  }
}

extern "C" void kernel_launch(void* const* d_in, const int* in_sizes, int n_in,
                              void* d_out, int out_size, void* d_ws, size_t ws_size,
                              hipStream_t stream) {
  const float* em = (const float*)d_in[0];
  const int* tags = (const int*)d_in[1];
  const float* trans = (const float*)d_in[2];
  const float* startv = (const float*)d_in[3];
  const float* endv = (const float*)d_in[4];
  float* out = (float*)d_out;
  char* ws = (char*)d_ws;
  float* fpart = (float*)(ws + 0);         // 64*32 f32 (8KB)
  float* gold = (float*)(ws + 8192);       // 64 f32
  int* best_last = (int*)(ws + 8448);      // 64 i32
  uint8_t* TOPa = (uint8_t*)(ws + 8704);   // 64*8 u8
  int* done_cnt = (int*)(ws + 9216);       // 1 i32 (clock-keeper exit flag)
  uint8_t* mmap = (uint8_t*)(ws + 9728);   // 64*1024 u8

  hipMemsetAsync(done_cnt, 0, 4, stream);  // re-arm the done counter per call
  scan_kernel<<<dim3(NB + 512 + NDUMMY), dim3(256), 0, stream>>>(
      em, trans, startv, endv, out, fpart, best_last, done_cnt);
  gold_kernel<<<dim3(64), dim3(256), 0, stream>>>(em, tags, trans, startv, endv, gold);
  maps_kernel<<<dim3(512), dim3(128), 0, stream>>>(out, mmap);
  boundary_kernel<<<dim3(1), dim3(64), 0, stream>>>(mmap, best_last, fpart, gold, TOPa, out);
  replay_kernel<<<dim3(512), dim3(128), 0, stream>>>(out, TOPa);
}

// Round 10
// 744.505 us; speedup vs baseline: 3.0436x; 1.7842x over previous
//
#include <hip/hip_runtime.h>
#include <stdint.h>

#define NB 64
#define NT 2048
#define NC 128
#define KF 32          // forward chunks per batch
#define LF 64          // forward chunk length
#define WF 16          // forward warmup steps

typedef _Float16 h2 __attribute__((ext_vector_type(2)));

__device__ __forceinline__ h2 bc2(uint32_t u) { return __builtin_bit_cast(h2, u); }

__device__ __forceinline__ float fdot2f(h2 a, h2 b, float c) {
#if __has_builtin(__builtin_amdgcn_fdot2)
  return __builtin_amdgcn_fdot2(a, b, c, false);
#else
  float d;
  asm("v_dot2_f32_f16 %0, %1, %2, %3"
      : "=v"(d)
      : "v"(__builtin_bit_cast(uint32_t, a)), "v"(__builtin_bit_cast(uint32_t, b)), "v"(c));
  return d;
#endif
}

#define DPP_FMAX_STAGE(vv, ctrl)                                               \
  {                                                                            \
    int t_ = __builtin_amdgcn_update_dpp(vv, vv, ctrl, 0xf, 0xf, false);       \
    vv = __builtin_bit_cast(int, fmaxf(__builtin_bit_cast(float, vv),          \
                                       __builtin_bit_cast(float, t_)));        \
  }

__device__ __forceinline__ float wave_max_bcast(float x) {
  int v = __builtin_bit_cast(int, x);
  DPP_FMAX_STAGE(v, 0x111);
  DPP_FMAX_STAGE(v, 0x112);
  DPP_FMAX_STAGE(v, 0x114);
  DPP_FMAX_STAGE(v, 0x118);
  DPP_FMAX_STAGE(v, 0x142);
  DPP_FMAX_STAGE(v, 0x143);
  return __builtin_bit_cast(float, __builtin_amdgcn_readlane(v, 63));
}

__device__ __forceinline__ float readlanef(float v, int l) {
  return __builtin_bit_cast(float, __builtin_amdgcn_readlane(__builtin_bit_cast(int, v), l));
}

__device__ __forceinline__ int mbcnt64(unsigned long long m) {
  return __builtin_amdgcn_mbcnt_hi((uint32_t)(m >> 32),
                                   __builtin_amdgcn_mbcnt_lo((uint32_t)m, 0));
}

// Byte offset of one-hot row (b,t) inside d_out (floats: 64 nll + (b*T+t)*128).
// Slot layout during compute: [0,128) bp u8; [128,144) masks m0,m1;
// [144,512) survivor values f32 (cap 92). replay overwrites all 512B at the end.
__device__ __forceinline__ size_t slot_off(int b, int t) {
  return ((size_t)64 + ((size_t)b * NT + t) * NC) * 4;
}

union ScanSM {
  // viterbi: interleaved transitions, IT[l*256 + ct*2 + p] = T[2l+p][ct] (64KB).
  // One b128 at float offset (l*256 + 4*lane) yields
  // {T[2l][2lane], T[2l+1][2lane], T[2l][2lane+1], T[2l+1][2lane+1]}.
  float itr[64 * 256];
  uint32_t ea[4][2][64];      // forward: [wave][dbuf][lane] exp(alpha) fp16x2
};

// grid: blocks [0,NB) = viterbi (wave 0 only); [NB, NB+512) = forward, 4
// independent chunk-waves per block (no intra-block sync -> share LDS alloc).
__global__ __launch_bounds__(256, 1) void scan_kernel(
    const float* __restrict__ em, const float* __restrict__ trans,
    const float* __restrict__ startv, const float* __restrict__ endv,
    float* __restrict__ out, float* __restrict__ fpart, int* __restrict__ best_last) {
  __shared__ __align__(16) ScanSM sm;
  const int lane = threadIdx.x & 63;
  const int wid = threadIdx.x >> 6;

  if (blockIdx.x >= NB) {
    // ================= forward chunks (log partition pieces) =================
    const int fi = (blockIdx.x - NB) * 4 + wid;   // chunk id 0..2047
    const int b = fi >> 5, c = fi & 31;
    const int t0 = (c == 0) ? 0 : c * LF - WF;
    const int tend = (c == KF - 1) ? (NT - 1) : (c + 1) * LF;
    const float* emb = em + (size_t)b * NT * NC;

    h2 e0[64], e1[64];
#pragma unroll
    for (int j = 0; j < 64; ++j) {
      float2 r0 = *(const float2*)(trans + (size_t)(2 * j) * NC + 2 * lane);
      float2 r1 = *(const float2*)(trans + (size_t)(2 * j + 1) * NC + 2 * lane);
      h2 a, bb;
      a.x = (_Float16)__expf(r0.x);  a.y = (_Float16)__expf(r1.x);
      bb.x = (_Float16)__expf(r0.y); bb.y = (_Float16)__expf(r1.y);
      e0[j] = a; e1[j] = bb;
    }
    float2 ev = *(const float2*)(endv + 2 * lane);
    float2 em0 = *(const float2*)(emb + (size_t)t0 * NC + 2 * lane);
    float2 nx0 = *(const float2*)(emb + (size_t)(t0 + 1) * NC + 2 * lane);
    float2 nx1 = *(const float2*)(emb + (size_t)(t0 + 2) * NC + 2 * lane);
    float2 nx2 = *(const float2*)(emb + (size_t)(t0 + 3) * NC + 2 * lane);
    float2 nx3 = *(const float2*)(emb + (size_t)(t0 + 4) * NC + 2 * lane);
    float u0 = em0.x, u1 = em0.y;
    if (c == 0) {
      float2 sv = *(const float2*)(startv + 2 * lane);
      u0 += sv.x; u1 += sv.y;
    }
    float mu = 0.f;
    uint32_t* eab0 = &sm.ea[wid][0][0];
    uint32_t* eab1 = &sm.ea[wid][1][0];

    auto fstep = [&](int t, float2& nx) {
      h2 eh; eh.x = (_Float16)__expf(u0); eh.y = (_Float16)__expf(u1);
      uint32_t* eab = (t & 1) ? eab1 : eab0;
      eab[lane] = __builtin_bit_cast(uint32_t, eh);
      float nm = wave_max_bcast(fmaxf(u0, u1));  // overlaps LDS round-trip
      asm volatile("s_waitcnt lgkmcnt(0)" ::: "memory");
      float A0 = 0.f, A1 = 0.f, A2 = 0.f, A3 = 0.f;
#pragma unroll
      for (int q = 0; q < 16; ++q) {
        uint4 w = *(const uint4*)&eab[q * 4];
        A0 = fdot2f(bc2(w.x), e0[4 * q + 0], A0); A1 = fdot2f(bc2(w.x), e1[4 * q + 0], A1);
        A2 = fdot2f(bc2(w.y), e0[4 * q + 1], A2); A3 = fdot2f(bc2(w.y), e1[4 * q + 1], A3);
        A0 = fdot2f(bc2(w.z), e0[4 * q + 2], A0); A1 = fdot2f(bc2(w.z), e1[4 * q + 2], A1);
        A2 = fdot2f(bc2(w.w), e0[4 * q + 3], A2); A3 = fdot2f(bc2(w.w), e1[4 * q + 3], A3);
      }
      float o0 = nx.x - nm, o1 = nx.y - nm;
      u0 = __logf(A0 + A2) + o0;
      u1 = __logf(A1 + A3) + o1;
      mu += nm;
      if (t + 4 <= tend) nx = *(const float2*)(emb + (size_t)(t + 4) * NC + 2 * lane);
    };

    auto wave_lse = [&](float x0, float x1) -> float {
      float m = wave_max_bcast(fmaxf(x0, x1));
      float ss = __expf(x0 - m) + __expf(x1 - m);
#pragma unroll
      for (int s = 1; s < 64; s <<= 1) ss += __shfl_xor(ss, s, 64);
      return m + __logf(ss);
    };

    int t = t0 + 1;
    float m_start = 0.f;
    if (c > 0) {
      for (int j = 0; j < WF / 4; ++j) {
        fstep(t, nx0); fstep(t + 1, nx1); fstep(t + 2, nx2); fstep(t + 3, nx3);
        t += 4;
      }
      m_start = mu + wave_lse(u0, u1);
    }
    for (; t + 3 <= tend; t += 4) {
      fstep(t, nx0); fstep(t + 1, nx1); fstep(t + 2, nx2); fstep(t + 3, nx3);
    }
    int rem = tend - t + 1;  // 0..3
    if (rem > 0) fstep(t, nx0);
    if (rem > 1) fstep(t + 1, nx1);
    if (rem > 2) fstep(t + 2, nx2);

    float m_end;
    if (c == KF - 1) m_end = mu + wave_lse(u0 + ev.x, u1 + ev.y);
    else             m_end = mu + wave_lse(u0, u1);
    if (lane == 0) fpart[b * KF + c] = m_end - m_start;
  } else {
    // ====== viterbi phase 1: VALUE-ONLY pruned max-plus (argmax deferred) =====
    if (wid != 0) return;
    const int b = blockIdx.x;
    const float* emb = em + (size_t)b * NT * NC;
    char* ob = (char*)out;
    // build interleaved T (r6 layout; 0 bank conflicts measured)
    for (int r = 0; r < NC; ++r) {
      float2 w = *(const float2*)(trans + (size_t)r * NC + 2 * lane);
      int l = r >> 1, p = r & 1;
      sm.itr[l * 256 + (2 * lane) * 2 + p] = w.x;
      sm.itr[l * 256 + (2 * lane + 1) * 2 + p] = w.y;
    }
    asm volatile("s_waitcnt lgkmcnt(0)" ::: "memory");
    // per-row max/min for exact pruning: lane owns rows 2*lane (x/z), 2*lane+1 (y/w)
    float rmx0 = -INFINITY, rmn0 = INFINITY, rmx1 = -INFINITY, rmn1 = INFINITY;
    for (int j = 0; j < 64; ++j) {
      int jj = (j + lane) & 63;
      float4 q = *(const float4*)&sm.itr[lane * 256 + jj * 4];
      rmx0 = fmaxf(rmx0, fmaxf(q.x, q.z)); rmn0 = fminf(rmn0, fminf(q.x, q.z));
      rmx1 = fmaxf(rmx1, fmaxf(q.y, q.w)); rmn1 = fminf(rmn1, fminf(q.y, q.w));
    }

    float2 sv = *(const float2*)(startv + 2 * lane);
    float2 ev = *(const float2*)(endv + 2 * lane);
    float2 em0 = *(const float2*)(emb + 2 * lane);
    float2 nx0 = *(const float2*)(emb + (size_t)1 * NC + 2 * lane);
    float2 nx1 = *(const float2*)(emb + (size_t)2 * NC + 2 * lane);
    float2 nx2 = *(const float2*)(emb + (size_t)3 * NC + 2 * lane);
    float2 nx3 = *(const float2*)(emb + (size_t)4 * NC + 2 * lane);
    float v0 = sv.x + em0.x, v1 = sv.y + em0.y;  // v[2*lane], v[2*lane+1]
    const float4* itb = (const float4*)&sm.itr[4 * lane];

    // values-only candidate: extras/duplicates are harmless for a max
    auto vproc = [&](int l, float4 q, float& b0, float& b1) {
      float ve = readlanef(v0, l);
      float vo = readlanef(v1, l);
      b0 = fmaxf(b0, fmaxf(ve + q.x, vo + q.y));
      b1 = fmaxf(b1, fmaxf(ve + q.z, vo + q.w));
    };

    auto vstep = [&](int t, float2& nx) {
      // thr = max_cf fl(v[cf]+rowmin[cf]) <= winner(ct) for every ct (fp-monotone)
      float thr = wave_max_bcast(fmaxf(v0 + rmn0, v1 + rmn1));
      unsigned long long m0 = __ballot(v0 + rmx0 >= thr);   // even cf = 2*l
      unsigned long long m1 = __ballot(v1 + rmx1 >= thr);   // odd  cf = 2*l+1
      unsigned long long rem = m0 | m1;
      if (!rem) rem = 1ull;  // safety (cannot happen for finite inputs)
      int cnt = (int)__popcll(rem);
      char* rec = ob + slot_off(b, t);
      float best0 = -INFINITY, best1 = -INFINITY;

      if (__builtin_expect(cnt <= 92, 1)) {
        // ---- record store (off critical chain): masks + rank-compacted values
        if (lane == 0) {
          *(unsigned long long*)(rec + 128) = m0;
          *(unsigned long long*)(rec + 136) = m1;
        }
        int plt = mbcnt64(m0) + mbcnt64(m1);         // survivors strictly below lane
        int hasE = (int)((m0 >> lane) & 1ull);
        if (hasE) *(float*)(rec + 144 + 4 * plt) = v0;
        if ((m1 >> lane) & 1ull) *(float*)(rec + 144 + 4 * (plt + hasE)) = v1;
        // ---- values-only max over survivors (branchless enum, one LDS wait)
        unsigned long long r = rem;
        if (cnt <= 4) {
          int l0 = (int)__builtin_ctzll(r | 1ull); r &= r - 1;
          int l1 = (int)__builtin_ctzll(r | 1ull); r &= r - 1;
          int l2 = (int)__builtin_ctzll(r | 1ull); r &= r - 1;
          int l3 = (int)__builtin_ctzll(r | 1ull); r &= r - 1;
          float4 q0 = itb[l0 * 64], q1 = itb[l1 * 64], q2 = itb[l2 * 64], q3 = itb[l3 * 64];
          vproc(l0, q0, best0, best1); vproc(l1, q1, best0, best1);
          vproc(l2, q2, best0, best1); vproc(l3, q3, best0, best1);
        } else {
          int l0 = (int)__builtin_ctzll(r | 1ull); r &= r - 1;
          int l1 = (int)__builtin_ctzll(r | 1ull); r &= r - 1;
          int l2 = (int)__builtin_ctzll(r | 1ull); r &= r - 1;
          int l3 = (int)__builtin_ctzll(r | 1ull); r &= r - 1;
          int l4 = (int)__builtin_ctzll(r | 1ull); r &= r - 1;
          int l5 = (int)__builtin_ctzll(r | 1ull); r &= r - 1;
          int l6 = (int)__builtin_ctzll(r | 1ull); r &= r - 1;
          int l7 = (int)__builtin_ctzll(r | 1ull); r &= r - 1;
          float4 q0 = itb[l0 * 64], q1 = itb[l1 * 64], q2 = itb[l2 * 64], q3 = itb[l3 * 64];
          float4 q4 = itb[l4 * 64], q5 = itb[l5 * 64], q6 = itb[l6 * 64], q7 = itb[l7 * 64];
          vproc(l0, q0, best0, best1); vproc(l1, q1, best0, best1);
          vproc(l2, q2, best0, best1); vproc(l3, q3, best0, best1);
          vproc(l4, q4, best0, best1); vproc(l5, q5, best0, best1);
          vproc(l6, q6, best0, best1); vproc(l7, q7, best0, best1);
          while (r) {  // rare
            int la = (int)__builtin_ctzll(r | 1ull); r &= r - 1;
            int lb = (int)__builtin_ctzll(r | 1ull); r &= r - 1;
            int lc = (int)__builtin_ctzll(r | 1ull); r &= r - 1;
            int ld = (int)__builtin_ctzll(r | 1ull); r &= r - 1;
            float4 qa = itb[la * 64], qb = itb[lb * 64], qc = itb[lc * 64], qd = itb[ld * 64];
            vproc(la, qa, best0, best1); vproc(lb, qb, best0, best1);
            vproc(lc, qc, best0, best1); vproc(ld, qd, best0, best1);
          }
        }
      } else {
        // ---- overflow fallback (never in practice): exact inline argmax (r4)
        if (lane == 0) {
          *(unsigned long long*)(rec + 128) = 0ull;   // flag: bp already written
          *(unsigned long long*)(rec + 136) = 0ull;
        }
        int bi0 = 0, bi1 = 0;
        unsigned long long r = rem;
        do {
          int l0 = (int)__builtin_ctzll(r); r &= r - 1;
          int l1 = l0, l2 = l0, l3 = l0;
          if (r) {
            l1 = (int)__builtin_ctzll(r); r &= r - 1;
            if (r) {
              l2 = (int)__builtin_ctzll(r); r &= r - 1;
              if (r) { l3 = (int)__builtin_ctzll(r); r &= r - 1; }
            }
          }
          float4 q0 = itb[l0 * 64], q1 = itb[l1 * 64], q2 = itb[l2 * 64], q3 = itb[l3 * 64];
          auto proc = [&](int lc, float4 q) {
            if ((m0 >> lc) & 1ull) {
              float vce = readlanef(v0, lc);
              float s0 = vce + q.x, s1 = vce + q.z;
              bool g0 = s0 > best0; best0 = g0 ? s0 : best0; bi0 = g0 ? 2 * lc : bi0;
              bool g1 = s1 > best1; best1 = g1 ? s1 : best1; bi1 = g1 ? 2 * lc : bi1;
            }
            if ((m1 >> lc) & 1ull) {
              float vco = readlanef(v1, lc);
              float s0 = vco + q.y, s1 = vco + q.w;
              bool g0 = s0 > best0; best0 = g0 ? s0 : best0; bi0 = g0 ? 2 * lc + 1 : bi0;
              bool g1 = s1 > best1; best1 = g1 ? s1 : best1; bi1 = g1 ? 2 * lc + 1 : bi1;
            }
          };
          proc(l0, q0); proc(l1, q1); proc(l2, q2); proc(l3, q3);
        } while (r);
        *(uint16_t*)(rec + 2 * lane) = (uint16_t)((bi0 & 0xff) | (bi1 << 8));
      }

      v0 = best0 + nx.x; v1 = best1 + nx.y;
      if (t + 4 < NT) nx = *(const float2*)(emb + (size_t)(t + 4) * NC + 2 * lane);
    };
    int t = 1;
    for (; t + 3 < NT; t += 4) { vstep(t, nx0); vstep(t + 1, nx1); vstep(t + 2, nx2); vstep(t + 3, nx3); }
    vstep(t, nx0); vstep(t + 1, nx1); vstep(t + 2, nx2);  // t = 2045..2047

    v0 += ev.x; v1 += ev.y;
    float bv = v0; int bix = 2 * lane;
    if (v1 > bv) { bv = v1; bix = 2 * lane + 1; }
#pragma unroll
    for (int s = 1; s < 64; s <<= 1) {
      float ovv = __shfl_xor(bv, s, 64);
      int oi = __shfl_xor(bix, s, 64);
      if (ovv > bv || (ovv == bv && oi < bix)) { bv = ovv; bix = oi; }
    }
    if (lane == 0) best_last[b] = bix;
  }
}

// Phase 2: recompute backpointers exactly from (masks, survivor values).
// Non-survivors provably cannot tie the winner (fl(v+rmx) < thr <= best, strict),
// so first-index argmax over survivors (ascending cf, even-before-odd, strict '>')
// is bitwise identical to the reference argmax over all cf.
// grid: 64 batches x 32 sub-chunks of 64 rows; 128 threads = the ct dimension.
__global__ __launch_bounds__(128) void bp_kernel(const float* __restrict__ trans,
                                                 float* __restrict__ out) {
  int bid = blockIdx.x, b = bid >> 5, cc = bid & 31, ct = threadIdx.x;
  char* ob = (char*)out;
  int lo = cc * 64, hi = cc * 64 + 63;
  if (lo < 1) lo = 1;
  for (int t = lo; t <= hi; ++t) {
    char* rec = ob + slot_off(b, t);
    unsigned long long m0 = *(const unsigned long long*)(rec + 128);
    unsigned long long m1 = *(const unsigned long long*)(rec + 136);
    unsigned long long rem = m0 | m1;
    if (rem == 0ull) continue;            // overflow row: bp written in phase 1
    const float* vals = (const float*)(rec + 144);
    float best = -INFINITY;
    int bi = 0, idx = 0;
    do {
      int l = (int)__builtin_ctzll(rem); rem &= rem - 1;
      if ((m0 >> l) & 1ull) {
        float s = vals[idx++] + trans[(size_t)(2 * l) * NC + ct];
        if (s > best) { best = s; bi = 2 * l; }
      }
      if ((m1 >> l) & 1ull) {
        float s = vals[idx++] + trans[(size_t)(2 * l + 1) * NC + ct];
        if (s > best) { best = s; bi = 2 * l + 1; }
      }
    } while (rem);
    ((uint8_t*)rec)[ct] = (uint8_t)bi;
  }
}

__global__ __launch_bounds__(256) void gold_kernel(
    const float* __restrict__ em, const int* __restrict__ tags,
    const float* __restrict__ trans, const float* __restrict__ startv,
    const float* __restrict__ endv, float* __restrict__ gold) {
  __shared__ float red[256];
  int b = blockIdx.x, tid = threadIdx.x;
  const float* emb = em + (size_t)b * NT * NC;
  const int* tgb = tags + (size_t)b * NT;
  float acc = 0.f;
  for (int j = 0; j < NT / 256; ++j) {
    int t = tid + j * 256;
    int tg = tgb[t];
    acc += emb[(size_t)t * NC + tg];
    if (t < NT - 1) acc += trans[(size_t)tg * NC + tgb[t + 1]];
  }
  red[tid] = acc;
  __syncthreads();
  for (int s = 128; s > 0; s >>= 1) { if (tid < s) red[tid] += red[tid + s]; __syncthreads(); }
  if (tid == 0) gold[b] = red[0] + startv[tgb[0]] + endv[tgb[NT - 1]];
}

// Per (b,chunk): compose backpointers over the chunk -> 128->128 map.
__global__ __launch_bounds__(128) void maps_kernel(const float* __restrict__ out,
                                                   uint8_t* __restrict__ mmap) {
  __shared__ uint8_t bp[256 * 128];
  int bid = blockIdx.x, b = bid >> 3, c = bid & 7, tid = threadIdx.x;
  const char* ob = (const char*)out;
  int lo_t = c * 256 + 1;
  int nrows = (c == 7) ? 255 : 256;
  int nd = nrows * 32;
  for (int k = 0; k < 64; ++k) {
    int d = tid + k * 128;
    if (d < nd) {
      int row = d >> 5, col = d & 31;
      *(uint32_t*)&bp[(size_t)d * 4] =
          *(const uint32_t*)(ob + slot_off(b, lo_t + row) + (size_t)col * 4);
    }
  }
  __syncthreads();
  int cur = tid;
  for (int i = nrows - 1; i >= 0; --i) cur = bp[i * 128 + cur];
  mmap[b * 1024 + c * 128 + tid] = (uint8_t)cur;
}

// Combine maps: boundary states per chunk; also nll = sum(fpart) - gold.
__global__ void boundary_kernel(const uint8_t* __restrict__ mmap,
                                const int* __restrict__ best_last,
                                const float* __restrict__ fpart,
                                const float* __restrict__ gold,
                                uint8_t* __restrict__ TOPa,
                                float* __restrict__ out) {
  int b = threadIdx.x;
  const uint8_t* ob = (const uint8_t*)out;
  int e = best_last[b];                       // = path[2047]
  for (int c = 7; c >= 0; --c) {
    TOPa[b * 8 + c] = (c == 7) ? (uint8_t)e : ob[slot_off(b, 256 * (c + 1)) + e];
    e = mmap[b * 1024 + c * 128 + e];         // e = path[256c]
  }
  float z = 0.f;
  for (int c = 0; c < KF; ++c) z += fpart[b * KF + c];
  out[b] = z - gold[b];
}

// Replay each chunk from its known top state, emit one-hot rows (overwrites slots).
__global__ __launch_bounds__(128) void replay_kernel(float* __restrict__ out,
                                                     const uint8_t* __restrict__ TOPa) {
  __shared__ uint8_t bp[255 * 128];
  __shared__ uint8_t path[256];
  int bid = blockIdx.x, b = bid >> 3, c = bid & 7, tid = threadIdx.x;
  char* ob = (char*)out;
  int lo_t = c * 256 + 1;
  const int nd = 255 * 32;
  for (int k = 0; k < 64; ++k) {
    int d = tid + k * 128;
    if (d < nd) {
      int row = d >> 5, col = d & 31;
      *(uint32_t*)&bp[(size_t)d * 4] =
          *(const uint32_t*)(ob + slot_off(b, lo_t + row) + (size_t)col * 4);
    }
  }
  __syncthreads();
  if (tid == 0) {
    int cur = TOPa[b * 8 + c];
    path[255] = (uint8_t)cur;
    for (int i = 254; i >= 0; --i) { cur = bp[i * 128 + cur]; path[i] = (uint8_t)cur; }
  }
  __syncthreads();
  for (int k = 0; k < 64; ++k) {
    int idx = tid + k * 128;
    int row = idx >> 5, j = idx & 31;
    int p = path[row];
    int c0 = j * 4;
    float4 val;
    val.x = (c0 + 0 == p) ? 1.f : 0.f;
    val.y = (c0 + 1 == p) ? 1.f : 0.f;
    val.z = (c0 + 2 == p) ? 1.f : 0.f;
    val.w = (c0 + 3 == p) ? 1.f : 0.f;
    *(float4*)(ob + slot_off(b, c * 256 + row) + (size_t)j * 16) = val;
  }
}

extern "C" void kernel_launch(void* const* d_in, const int* in_sizes, int n_in,
                              void* d_out, int out_size, void* d_ws, size_t ws_size,
                              hipStream_t stream) {
  const float* em = (const float*)d_in[0];
  const int* tags = (const int*)d_in[1];
  const float* trans = (const float*)d_in[2];
  const float* startv = (const float*)d_in[3];
  const float* endv = (const float*)d_in[4];
  float* out = (float*)d_out;
  char* ws = (char*)d_ws;
  float* fpart = (float*)(ws + 0);         // 64*32 f32 (8KB)
  float* gold = (float*)(ws + 8192);       // 64 f32
  int* best_last = (int*)(ws + 8448);      // 64 i32
  uint8_t* TOPa = (uint8_t*)(ws + 8704);   // 64*8 u8
  uint8_t* mmap = (uint8_t*)(ws + 9216);   // 64*1024 u8

  scan_kernel<<<dim3(NB + 512), dim3(256), 0, stream>>>(em, trans, startv, endv, out,
                                                        fpart, best_last);
  bp_kernel<<<dim3(2048), dim3(128), 0, stream>>>(trans, out);
  gold_kernel<<<dim3(64), dim3(256), 0, stream>>>(em, tags, trans, startv, endv, gold);
  maps_kernel<<<dim3(512), dim3(128), 0, stream>>>(out, mmap);
  boundary_kernel<<<dim3(1), dim3(64), 0, stream>>>(mmap, best_last, fpart, gold, TOPa, out);
  replay_kernel<<<dim3(512), dim3(128), 0, stream>>>(out, TOPa);
}